// Round 5
// baseline (555.616 us; speedup 1.0000x reference)
//
#include <hip/hip_runtime.h>
#include <math.h>

// Problem constants
constexpr int BB  = 16;
constexpr int CH  = 96;            // CIN == COUT == 96
constexpr int HH  = 96;
constexpr int WW  = 96;
constexpr int HWI = HH * WW;       // 9216
constexpr int CHW = CH * HWI;      // 884736
constexpr int IMG = BB * CHW;      // elems per [B,C,H,W] tensor
constexpr int ATT = BB * CH * CH * 9;  // 1327104 floats
constexpr int WPK = 27 * 6 * 64 * 8;   // 82944 bf16 elems per packed weight matrix

typedef short short8 __attribute__((ext_vector_type(8)));
typedef float floatx4 __attribute__((ext_vector_type(4)));

__device__ __forceinline__ ushort f2bf(float f) {
  union { float f; unsigned u; } v; v.f = f;
  unsigned r = (v.u + 0x7fffu + ((v.u >> 16) & 1u)) >> 16;  // RNE
  return (ushort)r;
}

// ---------------------------------------------------------------------------
// NCHW fp32 -> NHWC bf16. One block per (b, h): read rows coalesced (float4
// along w), transpose through LDS, write fully-contiguous 18 KB NHWC row.
// ---------------------------------------------------------------------------
__global__ __launch_bounds__(256) void to_nhwc(
    const float* __restrict__ x, ushort* __restrict__ xh)
{
  const int b = blockIdx.y, h = blockIdx.x;
  __shared__ ushort Ls[96 * 104];
  const float* xb = x + (size_t)b * CHW + h * WW;
  for (int t = threadIdx.x; t < 96 * 24; t += 256) {
    const int c = t / 24, wq = t % 24;
    const float4 v = *(const float4*)(xb + (size_t)c * HWI + wq * 4);
    Ls[(wq * 4 + 0) * 104 + c] = f2bf(v.x);
    Ls[(wq * 4 + 1) * 104 + c] = f2bf(v.y);
    Ls[(wq * 4 + 2) * 104 + c] = f2bf(v.z);
    Ls[(wq * 4 + 3) * 104 + c] = f2bf(v.w);
  }
  __syncthreads();
  ushort* ob = xh + (size_t)b * CHW + (size_t)h * 96 * 96;
  for (int t = threadIdx.x; t < 96 * 12; t += 256) {
    const int w = t / 12, oct = t % 12;
    *(short8*)(ob + w * 96 + oct * 8) = *(const short8*)(&Ls[w * 104 + oct * 8]);
  }
}

// ---------------------------------------------------------------------------
// Weight prepack (unchanged): fp32 (m, ci, o) at src[m*864 + ci*9 + o] ->
// bf16 in MFMA A-frag lane order for K ordering k = o*96 + ci, chunks of 32.
// ---------------------------------------------------------------------------
__global__ __launch_bounds__(256) void prepack(
    const float* __restrict__ src, ushort* __restrict__ dst)
{
  const int g = blockIdx.y;
  const int p = blockIdx.x * 256 + threadIdx.x;   // 0..82943
  const float* s = src + (size_t)g * WPK;
  ushort* d = dst + (size_t)g * WPK;
  const int j    = p & 7;
  const int lane = (p >> 3) & 63;
  const int rest = p >> 9;                        // 0..161
  const int mt = rest % 6;
  const int kc = rest / 6;
  const int m  = mt * 16 + (lane & 15);
  const int k  = kc * 32 + (lane >> 4) * 8 + j;
  const int ci = k % 96;
  const int o  = k / 96;
  d[p] = f2bf(s[m * 864 + ci * 9 + o]);
}

// ===========================================================================
// Triple conv: Y1,Y2,Y3 = conv(x, W1/W2/W3), all sharing one LDS staging.
// Implicit GEMM, MFMA 16x16x32 bf16. Tile 4 rows x 32 cols (N=128), M=96,
// K=864 in 27 chunks. Halo 6x34=204 px x 96ci staged from NHWC (contiguous
// 16B/lane loads). 8 waves; wave wv owns 16 px (row wv>>1, colhalf wv&1).
// Per chunk per wave: 1 ds_read_b128 + 18 A-loads (L1-hot) + 18 MFMA.
// acc = 72 regs; __launch_bounds__(512,4) targets <=128 total -> 4 waves/SIMD.
// Outputs bounce through LDS -> contiguous NHWC bf16 stores.
// ===========================================================================
__global__ __launch_bounds__(512, 4) void conv_triple(
    const ushort* __restrict__ Xh,
    const ushort* __restrict__ Wp1, const ushort* __restrict__ Wp2,
    const ushort* __restrict__ Wp3,
    ushort* __restrict__ Y1, ushort* __restrict__ Y2, ushort* __restrict__ Y3)
{
  const int b    = blockIdx.y;
  const int tile = blockIdx.x;          // 0..71
  const int ty0  = (tile / 3) * 4;
  const int tx0  = (tile % 3) * 32;
  const int tid  = threadIdx.x;
  const int lane = tid & 63;
  const int wv   = tid >> 6;            // 0..7
  const int nc   = lane & 15;
  const int q    = lane >> 4;

  __shared__ ushort Xs[204 * 104];      // 42432 B

  // ---- stage halo 6x34 px x 96 ci from NHWC (16B per lane, contiguous) ----
  const ushort* xb = Xh + (size_t)b * CHW;
  for (int t = tid; t < 204 * 12; t += 512) {
    const int p  = t / 12, oct = t % 12;
    const int hr = p / 34, hc = p - hr * 34;
    const int gy = ty0 - 1 + hr, gx = tx0 - 1 + hc;
    short8 v = {0, 0, 0, 0, 0, 0, 0, 0};
    if (((unsigned)gy < 96u) & ((unsigned)gx < 96u))
      v = *(const short8*)(xb + ((size_t)(gy * 96 + gx)) * 96 + oct * 8);
    *(short8*)(&Xs[p * 104 + oct * 8]) = v;
  }
  __syncthreads();

  floatx4 acc[3][6];
#pragma unroll
  for (int v = 0; v < 3; ++v)
#pragma unroll
    for (int mt = 0; mt < 6; ++mt)
#pragma unroll
      for (int r = 0; r < 4; ++r) acc[v][mt][r] = 0.f;

  const int r0   = wv >> 1;             // tile row 0..3
  const int ch16 = (wv & 1) * 16;       // col half

  for (int o = 0; o < 9; ++o) {
    const int dy = o / 3, dx = o % 3;
    const int pbase = (r0 + dy) * 34 + ch16 + dx + nc;
#pragma unroll
    for (int cc = 0; cc < 3; ++cc) {
      const int kc = o * 3 + cc;
      const short8 bf = *(const short8*)(&Xs[pbase * 104 + cc * 32 + q * 8]);
      const size_t abase = (size_t)kc * 3072 + lane * 8;
      const ushort* a1 = Wp1 + abase;
      const ushort* a2 = Wp2 + abase;
      const ushort* a3 = Wp3 + abase;
#pragma unroll
      for (int mt = 0; mt < 6; ++mt) {
        acc[0][mt] = __builtin_amdgcn_mfma_f32_16x16x32_bf16(
            *(const short8*)(a1 + mt * 512), bf, acc[0][mt], 0, 0, 0);
        acc[1][mt] = __builtin_amdgcn_mfma_f32_16x16x32_bf16(
            *(const short8*)(a2 + mt * 512), bf, acc[1][mt], 0, 0, 0);
        acc[2][mt] = __builtin_amdgcn_mfma_f32_16x16x32_bf16(
            *(const short8*)(a3 + mt * 512), bf, acc[2][mt], 0, 0, 0);
      }
    }
  }

  // ---- epilogue: bounce each conv's tile through LDS -> NHWC stores ----
  ushort* const outs[3] = { Y1 + (size_t)b * CHW, Y2 + (size_t)b * CHW,
                            Y3 + (size_t)b * CHW };
#pragma unroll
  for (int v = 0; v < 3; ++v) {
    __syncthreads();
    const int px = wv * 16 + nc;        // 0..127
#pragma unroll
    for (int mt = 0; mt < 6; ++mt) {
      ushort4 u;
      u.x = f2bf(acc[v][mt][0]); u.y = f2bf(acc[v][mt][1]);
      u.z = f2bf(acc[v][mt][2]); u.w = f2bf(acc[v][mt][3]);
      *(ushort4*)(&Xs[px * 104 + mt * 16 + q * 4]) = u;
    }
    __syncthreads();
    ushort* yo = outs[v];
    for (int t = tid; t < 128 * 12; t += 512) {
      const int p = t / 12, oct = t % 12;
      const int gy = ty0 + (p >> 5), gx = tx0 + (p & 31);
      *(short8*)(yo + ((size_t)(gy * 96 + gx)) * 96 + oct * 8) =
          *(const short8*)(&Xs[p * 104 + oct * 8]);
    }
  }
}

// ===========================================================================
// Final attention-weighted conv: input Y3 NHWC bf16, per-batch packed
// weights, output d_out NCHW fp32 (64B-aligned row segments per co).
// ===========================================================================
__global__ __launch_bounds__(512, 4) void conv_final(
    const ushort* __restrict__ Xh, const ushort* __restrict__ Wpk,
    float* __restrict__ Out)
{
  const int b    = blockIdx.y;
  const int tile = blockIdx.x;
  const int ty0  = (tile / 3) * 4;
  const int tx0  = (tile % 3) * 32;
  const int tid  = threadIdx.x;
  const int lane = tid & 63;
  const int wv   = tid >> 6;
  const int nc   = lane & 15;
  const int q    = lane >> 4;

  __shared__ ushort Xs[204 * 104];

  const ushort* xb = Xh + (size_t)b * CHW;
  for (int t = tid; t < 204 * 12; t += 512) {
    const int p  = t / 12, oct = t % 12;
    const int hr = p / 34, hc = p - hr * 34;
    const int gy = ty0 - 1 + hr, gx = tx0 - 1 + hc;
    short8 v = {0, 0, 0, 0, 0, 0, 0, 0};
    if (((unsigned)gy < 96u) & ((unsigned)gx < 96u))
      v = *(const short8*)(xb + ((size_t)(gy * 96 + gx)) * 96 + oct * 8);
    *(short8*)(&Xs[p * 104 + oct * 8]) = v;
  }
  __syncthreads();

  const ushort* wp = Wpk + (size_t)b * WPK;

  floatx4 acc[6];
#pragma unroll
  for (int mt = 0; mt < 6; ++mt)
#pragma unroll
    for (int r = 0; r < 4; ++r) acc[mt][r] = 0.f;

  const int r0   = wv >> 1;
  const int ch16 = (wv & 1) * 16;

  for (int o = 0; o < 9; ++o) {
    const int dy = o / 3, dx = o % 3;
    const int pbase = (r0 + dy) * 34 + ch16 + dx + nc;
#pragma unroll
    for (int cc = 0; cc < 3; ++cc) {
      const int kc = o * 3 + cc;
      const short8 bf = *(const short8*)(&Xs[pbase * 104 + cc * 32 + q * 8]);
      const ushort* ap = wp + (size_t)kc * 3072 + lane * 8;
#pragma unroll
      for (int mt = 0; mt < 6; ++mt)
        acc[mt] = __builtin_amdgcn_mfma_f32_16x16x32_bf16(
            *(const short8*)(ap + mt * 512), bf, acc[mt], 0, 0, 0);
    }
  }

  // NCHW fp32 stores: 16 lanes consecutive gx -> aligned 64B segments
  float* yo = Out + (size_t)b * CHW;
  const int gy = ty0 + r0;
  const int gx = tx0 + ch16 + nc;
#pragma unroll
  for (int mt = 0; mt < 6; ++mt)
#pragma unroll
    for (int r = 0; r < 4; ++r) {
      const int co = mt * 16 + q * 4 + r;
      yo[(size_t)co * HWI + gy * 96 + gx] = acc[mt][r];
    }
}

// ---------------------------------------------------------------------------
// Attention Gram GEMM via MFMA, NHWC bf16 inputs.
// attn[b,k,c,d] = sum_{p in class-k 32x32 grid} Y1[b,c,p] * Y2[b,d,p].
// One block per (b,k); K=1024 in 16 slabs of 64 class-pixels. Staging reads
// contiguous 192B channel runs per class-pixel and transposes into
// [c][p]-major LDS via scalar writes. Compute section: proven r3/r4 code.
// ---------------------------------------------------------------------------
__global__ __launch_bounds__(1024) void attn_mfma(
    const ushort* __restrict__ Y1, const ushort* __restrict__ Y2,
    float* __restrict__ attnT)
{
  const int b  = blockIdx.x / 9;
  const int k  = blockIdx.x % 9;
  const int kh = k / 3, kw = k % 3;
  const int tid  = threadIdx.x;
  const int lane = tid & 63;
  const int wv   = tid >> 6;          // 0..15

  __shared__ ushort Ah[96 * 72], Bh[96 * 72];

  const ushort* y1b = Y1 + (size_t)b * CHW;
  const ushort* y2b = Y2 + (size_t)b * CHW;

  const int mg = wv / 3;
  const int ng = wv % 3;
  const int cn = lane & 15;
  const int q  = lane >> 4;

  floatx4 acc[2][2];
#pragma unroll
  for (int i = 0; i < 2; ++i)
#pragma unroll
    for (int j = 0; j < 2; ++j)
#pragma unroll
      for (int r = 0; r < 4; ++r) acc[i][j][r] = 0.f;

  const int sp   = tid / 12;          // class-pixel 0..63 (threads < 768)
  const int soct = tid % 12;          // channel octet
  const int sii  = sp >> 5, ssj = sp & 31;
  const int scol = 3 * ssj + kw;

  for (int s = 0; s < 16; ++s) {
    __syncthreads();
    if (tid < 768) {
      const int row = 3 * (2 * s + sii) + kh;
      const size_t g = ((size_t)(row * 96 + scol)) * 96 + soct * 8;
      const short8 v1 = *(const short8*)(y1b + g);
      const short8 v2 = *(const short8*)(y2b + g);
#pragma unroll
      for (int u = 0; u < 8; ++u) {
        Ah[(soct * 8 + u) * 72 + sp] = (ushort)v1[u];
        Bh[(soct * 8 + u) * 72 + sp] = (ushort)v2[u];
      }
    }
    __syncthreads();

    if (wv < 9) {
#pragma unroll
      for (int kc = 0; kc < 2; ++kc) {
        short8 ah[2], bh[2];
#pragma unroll
        for (int t = 0; t < 2; ++t) {
          ah[t] = *(const short8*)(&Ah[((mg * 2 + t) * 16 + cn) * 72 + kc * 32 + q * 8]);
          bh[t] = *(const short8*)(&Bh[((ng * 2 + t) * 16 + cn) * 72 + kc * 32 + q * 8]);
        }
#pragma unroll
        for (int i = 0; i < 2; ++i)
#pragma unroll
          for (int j = 0; j < 2; ++j)
            acc[i][j] = __builtin_amdgcn_mfma_f32_16x16x32_bf16(
                ah[i], bh[j], acc[i][j], 0, 0, 0);
      }
    }
  }

  if (wv < 9) {
#pragma unroll
    for (int i = 0; i < 2; ++i)
#pragma unroll
      for (int j = 0; j < 2; ++j)
#pragma unroll
        for (int r = 0; r < 4; ++r) {
          const int c = (mg * 2 + i) * 16 + q * 4 + r;
          const int d = (ng * 2 + j) * 16 + cn;
          attnT[((size_t)(b * CH + d) * CH + c) * 9 + k] = acc[i][j][r];
        }
  }
}

// ---------------------------------------------------------------------------
// Softmax over m = c*9+k (864 values) per (b,d) row (unchanged).
// ---------------------------------------------------------------------------
__global__ __launch_bounds__(256) void softmax_k(
    const float* __restrict__ attnT, float* __restrict__ attnW)
{
  const int bd = blockIdx.x;
  const float* src = attnT + (size_t)bd * 864;
  float* dst = attnW + (size_t)bd * 864;
  const float rs = 0.0340216824f;          // 1/sqrt(864)
  const int tid = threadIdx.x;

  float v0 = src[tid];
  float v1 = src[tid + 256];
  float v2 = src[tid + 512];
  float v3 = (tid < 96) ? src[tid + 768] : -3.0e38f;

  float mx = fmaxf(fmaxf(v0, v1), fmaxf(v2, v3));

  __shared__ float red[256];
  red[tid] = mx;
  __syncthreads();
#pragma unroll
  for (int s = 128; s > 0; s >>= 1) {
    if (tid < s) red[tid] = fmaxf(red[tid], red[tid + s]);
    __syncthreads();
  }
  mx = red[0];
  __syncthreads();

  const float e0 = expf((v0 - mx) * rs);
  const float e1 = expf((v1 - mx) * rs);
  const float e2 = expf((v2 - mx) * rs);
  const float e3 = (tid < 96) ? expf((v3 - mx) * rs) : 0.f;

  red[tid] = e0 + e1 + e2 + e3;
  __syncthreads();
#pragma unroll
  for (int s = 128; s > 0; s >>= 1) {
    if (tid < s) red[tid] += red[tid + s];
    __syncthreads();
  }
  const float inv = 1.f / red[0];

  dst[tid]       = e0 * inv;
  dst[tid + 256] = e1 * inv;
  dst[tid + 512] = e2 * inv;
  if (tid < 96) dst[tid + 768] = e3 * inv;
}

// ---------------------------------------------------------------------------
extern "C" void kernel_launch(void* const* d_in, const int* in_sizes, int n_in,
                              void* d_out, int out_size, void* d_ws, size_t ws_size,
                              hipStream_t stream)
{
  const float* x  = (const float*)d_in[0];
  const float* W1 = (const float*)d_in[1];
  const float* W2 = (const float*)d_in[2];
  const float* W3 = (const float*)d_in[3];

  ushort* Xh   = (ushort*)d_ws;                     // IMG bf16 (NHWC)
  ushort* Y1   = Xh + (size_t)IMG;                  // IMG bf16 (NHWC)
  ushort* Y2   = Y1 + (size_t)IMG;                  // IMG bf16 (NHWC)
  ushort* Y3   = Y2 + (size_t)IMG;                  // IMG bf16 (NHWC)
  float* attnT = (float*)(Y3 + (size_t)IMG);        // ATT fp32
  float* attnW = attnT + ATT;                       // ATT fp32
  ushort* pk   = (ushort*)(attnW + ATT);
  ushort* pkW1 = pk;
  ushort* pkW2 = pk + WPK;
  ushort* pkW3 = pk + 2 * (size_t)WPK;
  ushort* pkAW = pk + 3 * (size_t)WPK;              // 16 batch matrices
  // ws use: 4*IMG*2 + 2*ATT*4 + 19*WPK*2 bytes ~= 127 MB

  to_nhwc  <<<dim3(96, BB), 256, 0, stream>>>(x, Xh);

  prepack  <<<dim3(324, 1), 256, 0, stream>>>(W1, pkW1);
  prepack  <<<dim3(324, 1), 256, 0, stream>>>(W2, pkW2);
  prepack  <<<dim3(324, 1), 256, 0, stream>>>(W3, pkW3);

  conv_triple<<<dim3(72, BB), 512, 0, stream>>>(Xh, pkW1, pkW2, pkW3,
                                                Y1, Y2, Y3);

  attn_mfma<<<BB * 9, 1024, 0, stream>>>(Y1, Y2, attnT);
  softmax_k<<<BB * CH, 256, 0, stream>>>(attnT, attnW);

  prepack  <<<dim3(324, BB), 256, 0, stream>>>(attnW, pkAW);

  conv_final<<<dim3(72, BB), 512, 0, stream>>>(Y3, pkAW, (float*)d_out);
}